// Round 6
// baseline (406.051 us; speedup 1.0000x reference)
//
#include <hip/hip_runtime.h>

typedef __attribute__((ext_vector_type(8))) _Float16 half8;
typedef __attribute__((ext_vector_type(4))) _Float16 half4;
typedef __attribute__((ext_vector_type(4))) float f32x4;

// ---------- elementwise: fp32 -> fp16 ----------
__global__ __launch_bounds__(256) void conv4_k(const float4* __restrict__ in,
                                               half4* __restrict__ out){
  int i = blockIdx.x * 256 + threadIdx.x;
  float4 v = in[i];
  half4 h = { (_Float16)v.x, (_Float16)v.y, (_Float16)v.z, (_Float16)v.w };
  out[i] = h;
}

// ---------- mask dtype detection ----------
__global__ void mask_detect(const unsigned int* __restrict__ m, int* __restrict__ flag){
  if (threadIdx.x == 0 && blockIdx.x == 0){
    int ok = 1;
#pragma unroll
    for (int j = 0; j < 16; j++){
      unsigned v = m[j];
      if (v != 0u && v != 1u && v != 0x3f800000u) ok = 0;
    }
    *flag = ok;
  }
}

// ---------- row softmax over 2048 fp32 -> fp16 P ----------
__global__ __launch_bounds__(256) void softmax2048(const float* __restrict__ S,
                                                   _Float16* __restrict__ P){
  const long row = blockIdx.x;
  const float* s = S + row * 2048;
  _Float16* p = P + row * 2048;
  const int tid = threadIdx.x;
  float v[8];
  float m = -1e30f;
#pragma unroll
  for (int i = 0; i < 8; i++){ v[i] = s[tid + i * 256]; m = fmaxf(m, v[i]); }
#pragma unroll
  for (int o = 32; o; o >>= 1) m = fmaxf(m, __shfl_xor(m, o));
  __shared__ float rm[4], rs[4];
  if ((tid & 63) == 0) rm[tid >> 6] = m;
  __syncthreads();
  m = fmaxf(fmaxf(rm[0], rm[1]), fmaxf(rm[2], rm[3]));
  float sum = 0.f;
#pragma unroll
  for (int i = 0; i < 8; i++){ v[i] = __expf(v[i] - m); sum += v[i]; }
#pragma unroll
  for (int o = 32; o; o >>= 1) sum += __shfl_xor(sum, o);
  if ((tid & 63) == 0) rs[tid >> 6] = sum;
  __syncthreads();
  sum = rs[0] + rs[1] + rs[2] + rs[3];
  const float inv = 1.0f / sum;
#pragma unroll
  for (int i = 0; i < 8; i++) p[tid + i * 256] = (_Float16)(v[i] * inv);
}

// ---------- GEMM: C(Mx(64*NREP*gy)) = A(MxK) @ B(NxK)^T, fp16 in / fp32 accum ----------
// 8-phase (NREP=4) / 4-phase (NREP=2) schedule with counted vmcnt (T3+T4) + setprio (T5).
// BM=256, BN=64*NREP, BK=64, 512 threads = 8 waves (2Mx4N), per-wave 128 x 16*NREP.
// Staging of K-tile t+1 is spread 1 chunk (2 global_load_lds) per phase across tile t;
// the wait is vmcnt(2|4) AFTER issuing the first chunk(s) of t+1 -> tile t's loads
// (the oldest) are guaranteed complete, newest stay in flight. Never vmcnt(0) mid-loop.
// EPI: 0 fp32 (+bias) | 1 fp32 masked (scores) | 2 fp16 (+bias) | 4 fp16 transposed VT
#define GLL(gp, ldsoff) \
  __builtin_amdgcn_global_load_lds((const __attribute__((address_space(1))) void*)(gp), \
                                   (__attribute__((address_space(3))) void*)&lds[ldsoff], 16, 0, 0)
#define BAR() asm volatile("s_barrier" ::: "memory")
#define VMCNT(n) asm volatile("s_waitcnt vmcnt(" #n ")" ::: "memory")

template<int EPI, int NREP>
__global__ __launch_bounds__(512, 2)
void gemm256(const unsigned short* __restrict__ A, const unsigned short* __restrict__ B,
             int lda, int ldb, int K, const float* __restrict__ bias,
             const void* __restrict__ mask, const int* __restrict__ maskFlag,
             void* __restrict__ out0, int ldc, long aBS, long bBS, long oBS, int maskBS)
{
  constexpr int BN     = 64 * NREP;
  constexpr int BUFSZ  = 16384 + 4096 * NREP;   // elements per dbuf (A 256x64 + B BNx64)
  constexpr int NCHUNK = 2 + NREP / 2;          // 16KB staging chunks per K-tile
  __shared__ short lds[2 * BUFSZ];              // 128KB (NREP=4) / 96KB (NREP=2)

  const int z = blockIdx.z;
  const long zA = (long)z * aBS, zB = (long)z * bBS;
  const int tid = threadIdx.x;
  const int lane = tid & 63, wid = tid >> 6;
  const int wr = wid >> 2, wc = wid & 3;
  const int fr = lane & 15, fk = lane >> 4;
  const int brow = blockIdx.x * 256, bcol = blockIdx.y * BN;

  f32x4 acc[8][NREP];
  const f32x4 fzero = {0.f, 0.f, 0.f, 0.f};
#pragma unroll
  for (int i = 0; i < 8; i++)
#pragma unroll
    for (int j = 0; j < NREP; j++) acc[i][j] = fzero;

  const int srow = tid >> 3, scol = (tid & 7) * 8;      // staging: row tid/8, col (tid%8)*8
  const unsigned short* Ag = A + zA + (long)(brow + srow) * lda + scol;
  const unsigned short* Bg = B + zB + (long)(bcol + srow) * ldb + scol;
  const int aoff = (wr * 128 + fr) * 64 + fk * 8;
  const int boff = (wc * 16 * NREP + fr) * 64 + fk * 8;

  auto stage = [&](int nb, int c, long k1) {
    if (c < 2) {
      const unsigned short* g = Ag + (long)(c * 128) * lda + k1;
      GLL(g,                  nb + c * 8192 + tid * 8);
      GLL(g + (long)64 * lda, nb + c * 8192 + 4096 + tid * 8);
    } else {
      const unsigned short* g = Bg + (long)((c - 2) * 128) * ldb + k1;
      GLL(g,                  nb + 16384 + (c - 2) * 8192 + tid * 8);
      GLL(g + (long)64 * ldb, nb + 16384 + (c - 2) * 8192 + 4096 + tid * 8);
    }
  };

  half8 a[4][2], b[NREP][2];
  auto readA = [&](int cb, int qm) {
#pragma unroll
    for (int mi = 0; mi < 4; ++mi)
#pragma unroll
      for (int kk = 0; kk < 2; ++kk)
        a[mi][kk] = *(const half8*)&lds[cb + aoff + qm * 4096 + mi * 1024 + kk * 32];
  };
  auto readB = [&](int cb, int n0, int n1) {
#pragma unroll
    for (int ni = n0; ni < n1; ++ni)
#pragma unroll
      for (int kk = 0; kk < 2; ++kk)
        b[ni][kk] = *(const half8*)&lds[cb + 16384 + boff + ni * 1024 + kk * 32];
  };
  auto mmaQ = [&](int qm, int n0, int n1) {
#pragma unroll
    for (int mi = 0; mi < 4; ++mi)
#pragma unroll
      for (int ni = n0; ni < n1; ++ni) {
        f32x4 c = acc[qm * 4 + mi][ni];
        c = __builtin_amdgcn_mfma_f32_16x16x32_f16(a[mi][0], b[ni][0], c, 0, 0, 0);
        c = __builtin_amdgcn_mfma_f32_16x16x32_f16(a[mi][1], b[ni][1], c, 0, 0, 0);
        acc[qm * 4 + mi][ni] = c;
      }
  };

  const int nt = K >> 6;
  for (int c = 0; c < NCHUNK; ++c) stage(0, c, 0);   // prologue: K-tile 0 -> buf0

  for (int t = 0; t < nt; ++t) {
    const int cb = (t & 1) ? BUFSZ : 0, nb = cb ^ BUFSZ;
    const long k1 = (long)(t + 1) << 6;
    const bool pf = (t + 1 < nt);
    if constexpr (NREP == 4) {
      // ph0: quadrant (qm0, qn0)
      if (pf) { stage(nb, 0, k1); VMCNT(2); } else VMCNT(0);
      BAR();
      readA(cb, 0); readB(cb, 0, 2);
      __builtin_amdgcn_s_setprio(1); mmaQ(0, 0, 2); __builtin_amdgcn_s_setprio(0);
      BAR();
      // ph1: (qm0, qn1)
      if (pf) stage(nb, 1, k1);
      readB(cb, 2, 4);
      BAR();
      __builtin_amdgcn_s_setprio(1); mmaQ(0, 2, 4); __builtin_amdgcn_s_setprio(0);
      BAR();
      // ph2: (qm1, qn1)
      if (pf) stage(nb, 2, k1);
      readA(cb, 1);
      BAR();
      __builtin_amdgcn_s_setprio(1); mmaQ(1, 2, 4); __builtin_amdgcn_s_setprio(0);
      BAR();
      // ph3: (qm1, qn0) — all operands already resident
      if (pf) stage(nb, 3, k1);
      BAR();
      __builtin_amdgcn_s_setprio(1); mmaQ(1, 0, 2); __builtin_amdgcn_s_setprio(0);
      BAR();
    } else {
      // ph0: qm0, all ni
      if (pf) { stage(nb, 0, k1); stage(nb, 1, k1); VMCNT(4); } else VMCNT(0);
      BAR();
      readA(cb, 0); readB(cb, 0, 2);
      __builtin_amdgcn_s_setprio(1); mmaQ(0, 0, 2); __builtin_amdgcn_s_setprio(0);
      BAR();
      // ph1: qm1
      if (pf) stage(nb, 2, k1);
      readA(cb, 1);
      BAR();
      __builtin_amdgcn_s_setprio(1); mmaQ(1, 0, 2); __builtin_amdgcn_s_setprio(0);
      BAR();
    }
  }

  // epilogue: C/D frag layout col=lane&15, row=(lane>>4)*4+r  [m89-verified]
  const long zO = (long)z * oBS;
  int mflag = 0;
  if constexpr (EPI == 1) mflag = *maskFlag;
#pragma unroll
  for (int mi = 0; mi < 8; ++mi) {
#pragma unroll
    for (int ni = 0; ni < NREP; ++ni) {
      const int col = bcol + wc * 16 * NREP + ni * 16 + fr;
      float bv = 0.f;
      if constexpr (EPI != 1) { if (bias) bv = bias[col]; }
      bool msk = false;
      if constexpr (EPI == 1) {
        msk = mflag ? (((const int*)mask)[(long)z * maskBS + col] != 0)
                    : (((const unsigned char*)mask)[(long)z * maskBS + col] != 0);
      }
#pragma unroll
      for (int r = 0; r < 4; ++r) {
        const int row = brow + wr * 128 + mi * 16 + fk * 4 + r;
        float v = acc[mi][ni][r] + bv;
        if constexpr (EPI == 0) {
          ((float*)out0)[zO + (long)row * ldc + col] = v;
        } else if constexpr (EPI == 1) {
          ((float*)out0)[zO + (long)row * ldc + col] = msk ? -1e30f : v;
        } else if constexpr (EPI == 2) {
          ((_Float16*)out0)[zO + (long)row * ldc + col] = (_Float16)v;
        } else {
          const int bb = row >> 11, tt = row & 2047;
          ((_Float16*)out0)[(long)bb * 2048 * 1024 + (long)col * 2048 + tt] = (_Float16)v;
        }
      }
    }
  }
}

extern "C" void kernel_launch(void* const* d_in, const int* in_sizes, int n_in,
                              void* d_out, int out_size, void* d_ws, size_t ws_size,
                              hipStream_t stream)
{
  (void)in_sizes; (void)n_in; (void)out_size; (void)ws_size;
  const float* query = (const float*)d_in[0];   // (4,2048,1024)
  const float* key   = (const float*)d_in[1];   // (4,2048,1024)
  const void*  kmask = d_in[2];                 // (4,2048) bool -> dtype detected on device
  const float* Wq    = (const float*)d_in[3];   // (1024,1024)
  const float* bq    = (const float*)d_in[4];
  const float* Wk    = (const float*)d_in[5];   // (2048,1024)
  const float* bk    = (const float*)d_in[6];
  const float* Wfc   = (const float*)d_in[7];   // (1024,1024)
  const float* bfc   = (const float*)d_in[8];
  float* out = (float*)d_out;

  char* ws = (char*)d_ws;
  size_t o = 0;
  auto take = [&](size_t bytes)->char*{
    char* p = ws + o;
    o += (bytes + 255) & ~(size_t)255;
    return p;
  };
  const size_t SZ_H = (size_t)8192 * 1024 * 2;      // 16.78 MB (8192x1024 fp16)

  int* maskFlag           = (int*)take(256);
  unsigned short* query_h = (unsigned short*)take(SZ_H);
  unsigned short* key_h   = (unsigned short*)take(SZ_H);
  unsigned short* Wq_h    = (unsigned short*)take((size_t)1024 * 1024 * 2);
  unsigned short* Wk_h    = (unsigned short*)take((size_t)2048 * 1024 * 2);
  unsigned short* Wfc_h   = (unsigned short*)take((size_t)1024 * 1024 * 2);
  unsigned short* Q       = (unsigned short*)take(SZ_H);
  unsigned short* K       = (unsigned short*)take(SZ_H);
  unsigned short* VT      = (unsigned short*)take(SZ_H);
  unsigned short* O       = (unsigned short*)take(SZ_H);
  float*          S       = (float*)take((size_t)8192 * 2048 * 4);   // 67.1 MB
  unsigned short* P       = (unsigned short*)take((size_t)8192 * 2048 * 2); // 33.6 MB

  mask_detect<<<1, 64, 0, stream>>>((const unsigned int*)kmask, maskFlag);

  conv4_k<<<8192, 256, 0, stream>>>((const float4*)query, (half4*)query_h);
  conv4_k<<<8192, 256, 0, stream>>>((const float4*)key,   (half4*)key_h);
  conv4_k<<<1024, 256, 0, stream>>>((const float4*)Wq,    (half4*)Wq_h);
  conv4_k<<<2048, 256, 0, stream>>>((const float4*)Wk,    (half4*)Wk_h);
  conv4_k<<<1024, 256, 0, stream>>>((const float4*)Wfc,   (half4*)Wfc_h);

  // Q = query @ Wq^T + bq   (8192x1024, K=1024) -> fp16   [BN=128: 32x8=256 blocks]
  gemm256<2, 2><<<dim3(32, 8, 1), 512, 0, stream>>>(
      query_h, Wq_h, 1024, 1024, 1024,
      bq, nullptr, nullptr, Q, 1024, 0, 0, 0, 0);

  // K = key @ Wk[0:1024]^T + bk[0:1024] -> fp16
  gemm256<2, 2><<<dim3(32, 8, 1), 512, 0, stream>>>(
      key_h, Wk_h, 1024, 1024, 1024,
      bk, nullptr, nullptr, K, 1024, 0, 0, 0, 0);

  // V = key @ Wk[1024:2048]^T + bk[1024:2048] -> VT (transposed per batch) fp16
  gemm256<4, 2><<<dim3(32, 8, 1), 512, 0, stream>>>(
      key_h, Wk_h + (size_t)1024 * 1024, 1024, 1024, 1024,
      bk + 1024, nullptr, nullptr, VT, 0, 0, 0, 0, 0);

  // scores: per batch S = Q @ K^T, masked  (2048x2048, K=1024) -> fp32  [BN=256: 8x8x4=256 blocks]
  gemm256<1, 4><<<dim3(8, 8, 4), 512, 0, stream>>>(
      Q, K, 1024, 1024, 1024,
      nullptr, kmask, maskFlag, S, 2048,
      (long)2048 * 1024, (long)2048 * 1024, (long)2048 * 2048, 2048);

  softmax2048<<<8192, 256, 0, stream>>>(S, (_Float16*)P);

  // O = P @ V  (per batch 2048x1024, K=2048; B = VT) -> fp16  [8x8x4=256 blocks]
  gemm256<2, 2><<<dim3(8, 8, 4), 512, 0, stream>>>(
      P, VT, 2048, 2048, 2048,
      nullptr, nullptr, nullptr, O, 1024,
      (long)2048 * 2048, (long)1024 * 2048, (long)2048 * 1024, 0);

  // out = O @ Wfc^T + bfc  (8192x1024, K=1024) -> fp32
  gemm256<0, 2><<<dim3(32, 8, 1), 512, 0, stream>>>(
      O, Wfc_h, 1024, 1024, 1024,
      bfc, nullptr, nullptr, out, 1024, 0, 0, 0, 0);
}

// Round 7
// 389.268 us; speedup vs baseline: 1.0431x; 1.0431x over previous
//
#include <hip/hip_runtime.h>

typedef __attribute__((ext_vector_type(8))) _Float16 half8;
typedef __attribute__((ext_vector_type(4))) _Float16 half4;
typedef __attribute__((ext_vector_type(4))) float f32x4;

// ---------- elementwise: fp32 -> fp16 ----------
__global__ __launch_bounds__(256) void conv4_k(const float4* __restrict__ in,
                                               half4* __restrict__ out){
  int i = blockIdx.x * 256 + threadIdx.x;
  float4 v = in[i];
  half4 h = { (_Float16)v.x, (_Float16)v.y, (_Float16)v.z, (_Float16)v.w };
  out[i] = h;
}

// ---------- mask dtype detection ----------
__global__ void mask_detect(const unsigned int* __restrict__ m, int* __restrict__ flag){
  if (threadIdx.x == 0 && blockIdx.x == 0){
    int ok = 1;
#pragma unroll
    for (int j = 0; j < 16; j++){
      unsigned v = m[j];
      if (v != 0u && v != 1u && v != 0x3f800000u) ok = 0;
    }
    *flag = ok;
  }
}

// ---------- row softmax over 2048 fp32 -> fp16 P ----------
__global__ __launch_bounds__(256) void softmax2048(const float* __restrict__ S,
                                                   _Float16* __restrict__ P){
  const long row = blockIdx.x;
  const float* s = S + row * 2048;
  _Float16* p = P + row * 2048;
  const int tid = threadIdx.x;
  float v[8];
  float m = -1e30f;
#pragma unroll
  for (int i = 0; i < 8; i++){ v[i] = s[tid + i * 256]; m = fmaxf(m, v[i]); }
#pragma unroll
  for (int o = 32; o; o >>= 1) m = fmaxf(m, __shfl_xor(m, o));
  __shared__ float rm[4], rs[4];
  if ((tid & 63) == 0) rm[tid >> 6] = m;
  __syncthreads();
  m = fmaxf(fmaxf(rm[0], rm[1]), fmaxf(rm[2], rm[3]));
  float sum = 0.f;
#pragma unroll
  for (int i = 0; i < 8; i++){ v[i] = __expf(v[i] - m); sum += v[i]; }
#pragma unroll
  for (int o = 32; o; o >>= 1) sum += __shfl_xor(sum, o);
  if ((tid & 63) == 0) rs[tid >> 6] = sum;
  __syncthreads();
  sum = rs[0] + rs[1] + rs[2] + rs[3];
  const float inv = 1.0f / sum;
#pragma unroll
  for (int i = 0; i < 8; i++) p[tid + i * 256] = (_Float16)(v[i] * inv);
}

// ---------- GEMM 256x256, 8-phase, counted vmcnt, setprio, T2 swizzle ----------
// C(MxN) = A(MxK) @ B(NxK)^T, fp16 in / fp32 accum. BM=BN=256, BK=64,
// 512 threads = 8 waves (2Mx4N). LDS 2x64KB double buffer, linear layout
// [64-row blocks][64 cols], 128B row stride.
// T2: logical col-granule g (16B units) lives at linear granule g^(row&7).
//   - staging: linear LDS dest (global_load_lds), global SOURCE col pre-swizzled
//     scol = ((tid&7)^(srow&7))*8   (rule 21: same involution both sides)
//   - ds_read: col offset ((kk*4+fk)^(fr&7))*8  -> all 32 banks uniform
// Phases: ph0 (qm0,n0-1) ph1 (qm0,n2-3) ph2 (qm1,n2-3) ph3 (qm1,n0-1);
// K-tile t+1's 4 staging chunks issue 1/phase; vmcnt(2) at ph0 waits tile t's
// 8 loads (oldest) leaving t+1 chunk0 in flight. Never vmcnt(0) mid-loop.
// EPI: 0 fp32 (+bias) | 1 fp32 masked (scores) | 2 fp16 (+bias)
//      5 fused KV: col<1024 -> K fp16 ; col>=1024 -> VT[b][col-1024][row&2047]
#define GLL(gp, ldsoff) \
  __builtin_amdgcn_global_load_lds((const __attribute__((address_space(1))) void*)(gp), \
                                   (__attribute__((address_space(3))) void*)&lds[ldsoff], 16, 0, 0)
#define BAR() asm volatile("s_barrier" ::: "memory")
#define VMCNT(n) asm volatile("s_waitcnt vmcnt(" #n ")" ::: "memory")

template<int EPI>
__global__ __launch_bounds__(512, 2)
void gemm256(const unsigned short* __restrict__ A, const unsigned short* __restrict__ B,
             int lda, int ldb, int K, const float* __restrict__ bias,
             const void* __restrict__ mask, const int* __restrict__ maskFlag,
             void* __restrict__ out0, void* __restrict__ out1, int ldc,
             long aBS, long bBS, long oBS, int maskBS)
{
  constexpr int BUFSZ = 32768;                  // elements: A 256x64 + B 256x64
  __shared__ short lds[2 * BUFSZ];              // 128 KB

  const int z = blockIdx.z;
  const long zA = (long)z * aBS, zB = (long)z * bBS;
  const int tid = threadIdx.x;
  const int lane = tid & 63, wid = tid >> 6;
  const int wr = wid >> 2, wc = wid & 3;
  const int fr = lane & 15, fk = lane >> 4;
  const int brow = blockIdx.x * 256, bcol = blockIdx.y * 256;

  f32x4 acc[8][4];
  const f32x4 fzero = {0.f, 0.f, 0.f, 0.f};
#pragma unroll
  for (int i = 0; i < 8; i++)
#pragma unroll
    for (int j = 0; j < 4; j++) acc[i][j] = fzero;

  // staging: thread tid -> LDS linear granule (srow, tid&7); source col swizzled
  const int srow = tid >> 3;
  const int scol = ((tid & 7) ^ (srow & 7)) * 8;
  const unsigned short* Ag = A + zA + (long)(brow + srow) * lda + scol;
  const unsigned short* Bg = B + zB + (long)(bcol + srow) * ldb + scol;

  // ds_read swizzled col offsets (elements), per lane:
  const int frs = fr & 7;
  const int c0 = ((0 * 4 + fk) ^ frs) * 8;      // kk=0
  const int c1 = ((1 * 4 + fk) ^ frs) * 8;      // kk=1
  const int aRow = wr * 8192 + fr * 64;         // + qm*4096 + mi*1024 + c{0,1}
  const int bRow = wc * 4096 + fr * 64;         // + ni*1024 + c{0,1}  (B base +16384)

  auto stage = [&](int nb, int c, long k1) {
    if (c < 2) {
      const unsigned short* g = Ag + (long)(c * 128) * lda + k1;
      GLL(g,                  nb + c * 8192 + tid * 8);
      GLL(g + (long)64 * lda, nb + c * 8192 + 4096 + tid * 8);
    } else {
      const unsigned short* g = Bg + (long)((c - 2) * 128) * ldb + k1;
      GLL(g,                  nb + 16384 + (c - 2) * 8192 + tid * 8);
      GLL(g + (long)64 * ldb, nb + 16384 + (c - 2) * 8192 + 4096 + tid * 8);
    }
  };

  half8 a[4][2], b[4][2];
  auto readA = [&](int cb, int qm) {
#pragma unroll
    for (int mi = 0; mi < 4; ++mi) {
      const int e = cb + aRow + qm * 4096 + mi * 1024;
      a[mi][0] = *(const half8*)&lds[e + c0];
      a[mi][1] = *(const half8*)&lds[e + c1];
    }
  };
  auto readB = [&](int cb, int n0) {
#pragma unroll
    for (int i = 0; i < 2; ++i) {
      const int ni = n0 + i;
      const int e = cb + 16384 + bRow + ni * 1024;
      b[ni][0] = *(const half8*)&lds[e + c0];
      b[ni][1] = *(const half8*)&lds[e + c1];
    }
  };
  auto mmaQ = [&](int qm, int n0) {
#pragma unroll
    for (int mi = 0; mi < 4; ++mi)
#pragma unroll
      for (int i = 0; i < 2; ++i) {
        const int ni = n0 + i;
        f32x4 c = acc[qm * 4 + mi][ni];
        c = __builtin_amdgcn_mfma_f32_16x16x32_f16(a[mi][0], b[ni][0], c, 0, 0, 0);
        c = __builtin_amdgcn_mfma_f32_16x16x32_f16(a[mi][1], b[ni][1], c, 0, 0, 0);
        acc[qm * 4 + mi][ni] = c;
      }
  };

  const int nt = K >> 6;
  for (int c = 0; c < 4; ++c) stage(0, c, 0);   // prologue: K-tile 0 -> buf0

  for (int t = 0; t < nt; ++t) {
    const int cb = (t & 1) ? BUFSZ : 0, nb = cb ^ BUFSZ;
    const long k1 = (long)(t + 1) << 6;
    const bool pf = (t + 1 < nt);
    // ph0: (qm0, n0-1)
    if (pf) { stage(nb, 0, k1); VMCNT(2); } else VMCNT(0);
    BAR();
    readA(cb, 0); readB(cb, 0);
    __builtin_amdgcn_s_setprio(1); mmaQ(0, 0); __builtin_amdgcn_s_setprio(0);
    BAR();
    // ph1: (qm0, n2-3)
    if (pf) stage(nb, 1, k1);
    readB(cb, 2);
    BAR();
    __builtin_amdgcn_s_setprio(1); mmaQ(0, 2); __builtin_amdgcn_s_setprio(0);
    BAR();
    // ph2: (qm1, n2-3)
    if (pf) stage(nb, 2, k1);
    readA(cb, 1);
    BAR();
    __builtin_amdgcn_s_setprio(1); mmaQ(1, 2); __builtin_amdgcn_s_setprio(0);
    BAR();
    // ph3: (qm1, n0-1) — operands resident
    if (pf) stage(nb, 3, k1);
    BAR();
    __builtin_amdgcn_s_setprio(1); mmaQ(1, 0); __builtin_amdgcn_s_setprio(0);
    BAR();
  }

  // epilogue: C/D frag layout col=lane&15, row=(lane>>4)*4+r  [m89-verified]
  const long zO = (long)z * oBS;
  int mflag = 0;
  if constexpr (EPI == 1) mflag = *maskFlag;
#pragma unroll
  for (int mi = 0; mi < 8; ++mi) {
#pragma unroll
    for (int ni = 0; ni < 4; ++ni) {
      const int col = bcol + wc * 64 + ni * 16 + fr;
      float bv = 0.f;
      if constexpr (EPI != 1) { if (bias) bv = bias[col]; }
      bool msk = false;
      if constexpr (EPI == 1) {
        msk = mflag ? (((const int*)mask)[(long)z * maskBS + col] != 0)
                    : (((const unsigned char*)mask)[(long)z * maskBS + col] != 0);
      }
#pragma unroll
      for (int r = 0; r < 4; ++r) {
        const int row = brow + (wid >> 2) * 128 + mi * 16 + (lane >> 4) * 4 + r;
        float v = acc[mi][ni][r] + bv;
        if constexpr (EPI == 0) {
          ((float*)out0)[zO + (long)row * ldc + col] = v;
        } else if constexpr (EPI == 1) {
          ((float*)out0)[zO + (long)row * ldc + col] = msk ? -1e30f : v;
        } else if constexpr (EPI == 2) {
          ((_Float16*)out0)[zO + (long)row * ldc + col] = (_Float16)v;
        } else {                      // EPI==5: fused K | V^T
          if (col < 1024) {
            ((_Float16*)out0)[(long)row * 1024 + col] = (_Float16)v;
          } else {
            const int bb = row >> 11, tt = row & 2047;
            ((_Float16*)out1)[(long)bb * 2048 * 1024 + (long)(col - 1024) * 2048 + tt] = (_Float16)v;
          }
        }
      }
    }
  }
}

extern "C" void kernel_launch(void* const* d_in, const int* in_sizes, int n_in,
                              void* d_out, int out_size, void* d_ws, size_t ws_size,
                              hipStream_t stream)
{
  (void)in_sizes; (void)n_in; (void)out_size; (void)ws_size;
  const float* query = (const float*)d_in[0];   // (4,2048,1024)
  const float* key   = (const float*)d_in[1];   // (4,2048,1024)
  const void*  kmask = d_in[2];                 // (4,2048) bool -> dtype detected on device
  const float* Wq    = (const float*)d_in[3];   // (1024,1024)
  const float* bq    = (const float*)d_in[4];
  const float* Wk    = (const float*)d_in[5];   // (2048,1024)
  const float* bk    = (const float*)d_in[6];
  const float* Wfc   = (const float*)d_in[7];   // (1024,1024)
  const float* bfc   = (const float*)d_in[8];
  float* out = (float*)d_out;

  char* ws = (char*)d_ws;
  size_t o = 0;
  auto take = [&](size_t bytes)->char*{
    char* p = ws + o;
    o += (bytes + 255) & ~(size_t)255;
    return p;
  };
  const size_t SZ_H = (size_t)8192 * 1024 * 2;      // 16.78 MB (8192x1024 fp16)

  int* maskFlag           = (int*)take(256);
  unsigned short* query_h = (unsigned short*)take(SZ_H);
  unsigned short* key_h   = (unsigned short*)take(SZ_H);
  unsigned short* Wq_h    = (unsigned short*)take((size_t)1024 * 1024 * 2);
  unsigned short* Wk_h    = (unsigned short*)take((size_t)2048 * 1024 * 2);
  unsigned short* Wfc_h   = (unsigned short*)take((size_t)1024 * 1024 * 2);
  unsigned short* Q       = (unsigned short*)take(SZ_H);
  unsigned short* K       = (unsigned short*)take(SZ_H);
  unsigned short* VT      = (unsigned short*)take(SZ_H);
  unsigned short* O       = (unsigned short*)take(SZ_H);
  float*          S       = (float*)take((size_t)8192 * 2048 * 4);   // 67.1 MB
  unsigned short* P       = (unsigned short*)take((size_t)8192 * 2048 * 2); // 33.6 MB

  mask_detect<<<1, 64, 0, stream>>>((const unsigned int*)kmask, maskFlag);

  conv4_k<<<8192, 256, 0, stream>>>((const float4*)query, (half4*)query_h);
  conv4_k<<<8192, 256, 0, stream>>>((const float4*)key,   (half4*)key_h);
  conv4_k<<<1024, 256, 0, stream>>>((const float4*)Wq,    (half4*)Wq_h);
  conv4_k<<<2048, 256, 0, stream>>>((const float4*)Wk,    (half4*)Wk_h);
  conv4_k<<<1024, 256, 0, stream>>>((const float4*)Wfc,   (half4*)Wfc_h);

  // fused K|V: c = key @ Wk^T + bk  (8192x2048, K=1024); cols<1024 -> K, >=1024 -> VT
  gemm256<5><<<dim3(32, 8, 1), 512, 0, stream>>>(
      key_h, Wk_h, 1024, 1024, 1024,
      bk, nullptr, nullptr, K, VT, 1024, 0, 0, 0, 0);

  // Q = query @ Wq^T + bq   (8192x1024, K=1024) -> fp16
  gemm256<2><<<dim3(32, 4, 1), 512, 0, stream>>>(
      query_h, Wq_h, 1024, 1024, 1024,
      bq, nullptr, nullptr, Q, nullptr, 1024, 0, 0, 0, 0);

  // scores: per batch S = Q @ K^T, masked  (2048x2048, K=1024) -> fp32
  gemm256<1><<<dim3(8, 8, 4), 512, 0, stream>>>(
      Q, K, 1024, 1024, 1024,
      nullptr, kmask, maskFlag, S, nullptr, 2048,
      (long)2048 * 1024, (long)2048 * 1024, (long)2048 * 2048, 2048);

  softmax2048<<<8192, 256, 0, stream>>>(S, (_Float16*)P);

  // O = P @ V  (per batch 2048x1024, K=2048; B = VT) -> fp16
  gemm256<2><<<dim3(8, 4, 4), 512, 0, stream>>>(
      P, VT, 2048, 2048, 2048,
      nullptr, nullptr, nullptr, O, nullptr, 1024,
      (long)2048 * 2048, (long)1024 * 2048, (long)2048 * 1024, 0);

  // out = O @ Wfc^T + bfc  (8192x1024, K=1024) -> fp32
  gemm256<0><<<dim3(32, 4, 1), 512, 0, stream>>>(
      O, Wfc_h, 1024, 1024, 1024,
      bfc, nullptr, nullptr, out, nullptr, 1024, 0, 0, 0, 0);
}